// Round 1
// baseline (208.066 us; speedup 1.0000x reference)
//
#include <hip/hip_runtime.h>
#include <stdint.h>

typedef __attribute__((ext_vector_type(4))) float f32x4;
typedef __attribute__((ext_vector_type(8))) short bf16x8;

#define MFMA(a, b, c) __builtin_amdgcn_mfma_f32_16x16x32_bf16(a, b, c, 0, 0, 0)

__device__ __forceinline__ short f2b(float f) {
    uint32_t u = __builtin_bit_cast(uint32_t, f);
    u += 0x7fffu + ((u >> 16) & 1u);
    return (short)(u >> 16);
}

// ---------- cast [Wq;Wk;Wv;Wo] (fp32, each [256][256]) -> Wall bf16 [1024][256]
__global__ void k_cast_w(const float* __restrict__ Wq, const float* __restrict__ Wk,
                         const float* __restrict__ Wv, const float* __restrict__ Wo,
                         short* __restrict__ Wall) {
    int idx = blockIdx.x * 256 + threadIdx.x;   // grid = 1024 blocks
    int row = idx >> 8, col = idx & 255;
    float v;
    if (row < 256)      v = Wq[row * 256 + col];
    else if (row < 512) v = Wk[(row - 256) * 256 + col];
    else if (row < 768) v = Wv[(row - 512) * 256 + col];
    else                v = Wo[(row - 768) * 256 + col];
    Wall[idx] = f2b(v);
}

// ---------- transpose+cast x fp32 [256][2304] -> xt bf16 [2304][256]
__global__ void k_transpose_x(const float* __restrict__ x, short* __restrict__ xt) {
    __shared__ float tile[64][65];
    int pbase = blockIdx.x * 64, cbase = blockIdx.y * 64;  // grid (36,4)
    int tx = threadIdx.x & 63, tq = threadIdx.x >> 6;
    #pragma unroll
    for (int r = 0; r < 16; r++) {
        int row = tq * 16 + r;
        tile[row][tx] = x[(cbase + row) * 2304 + pbase + tx];
    }
    __syncthreads();
    #pragma unroll
    for (int r = 0; r < 16; r++) {
        int prow = tq * 16 + r;
        xt[(pbase + prow) * 256 + cbase + tx] = f2b(tile[tx][prow]);
    }
}

// ---------- QKV projection: C[768][2304] = Wall[0:768] @ x ; scatter to Qf/Kf/Vt
// Qf[n][64] bf16 (pre-scaled 1/8), Kf[n][64] bf16, Vt[64][9216] bf16, n = p*4+h
__global__ __launch_bounds__(256) void k_gemm_qkv(
    const short* __restrict__ Wall, const short* __restrict__ xt,
    const float* __restrict__ bq, const float* __restrict__ bk, const float* __restrict__ bv,
    short* __restrict__ Qf, short* __restrict__ Kf, short* __restrict__ Vt) {
    int t = threadIdx.x, wave = t >> 6, lane = t & 63, lr = lane & 15, lg = lane >> 4;
    int obase = blockIdx.x * 64 + wave * 16;   // grid.x = 12
    int pbase = blockIdx.y * 64;               // grid.y = 36
    const short* arow  = Wall + (obase + lr) * 256 + lg * 8;
    const short* brow0 = xt + (pbase +  0 + lr) * 256 + lg * 8;
    const short* brow1 = xt + (pbase + 16 + lr) * 256 + lg * 8;
    const short* brow2 = xt + (pbase + 32 + lr) * 256 + lg * 8;
    const short* brow3 = xt + (pbase + 48 + lr) * 256 + lg * 8;
    f32x4 acc0 = {0,0,0,0}, acc1 = {0,0,0,0}, acc2 = {0,0,0,0}, acc3 = {0,0,0,0};
    #pragma unroll
    for (int ks = 0; ks < 8; ks++) {
        bf16x8 a = *(const bf16x8*)(arow + ks * 32);
        acc0 = MFMA(a, *(const bf16x8*)(brow0 + ks * 32), acc0);
        acc1 = MFMA(a, *(const bf16x8*)(brow1 + ks * 32), acc1);
        acc2 = MFMA(a, *(const bf16x8*)(brow2 + ks * 32), acc2);
        acc3 = MFMA(a, *(const bf16x8*)(brow3 + ks * 32), acc3);
    }
    int w_idx = obase >> 8;  // 0=q 1=k 2=v, uniform per block
    const float* bias = (w_idx == 0) ? bq : (w_idx == 1) ? bk : bv;
    f32x4 accs[4] = {acc0, acc1, acc2, acc3};
    #pragma unroll
    for (int i = 0; i < 4; i++) {
        int o = obase + 4 * lg + i;
        int oo = o & 255;
        float b = bias[oo];
        int h = oo >> 6, d = oo & 63;
        #pragma unroll
        for (int ct = 0; ct < 4; ct++) {
            int p = pbase + ct * 16 + lr;
            float val = accs[ct][i] + b;
            int n = p * 4 + h;
            if (w_idx == 0)      Qf[n * 64 + d] = f2b(val * 0.125f);
            else if (w_idx == 1) Kf[n * 64 + d] = f2b(val);
            else                 Vt[d * 9216 + n] = f2b(val);
        }
    }
}

// ---------- flash attention: N=9216, d=64. Block = 8 waves x 512 thr; block owns
// 32 queries; wave w handles KV chunk [w*1152,(w+1)*1152); LDS combine.
// Swapped QK^T (mfma(K,Q) = S^T) with permuted K rows so S^T accumulator regs are
// exactly the B-fragment of mfma_16x16x32 for PV.
__global__ __launch_bounds__(512) void k_attn(
    const short* __restrict__ Qf, const short* __restrict__ Kf,
    const short* __restrict__ Vt, short* __restrict__ Of) {
    __shared__ float lds_m[8][32];
    __shared__ float lds_s[8][32];
    __shared__ float lds_acc[64][32];
    int t = threadIdx.x, wave = t >> 6, lane = t & 63, lr = lane & 15, lg = lane >> 4;
    int qbase = blockIdx.x * 32;   // grid = 288
    #pragma unroll
    for (int r = 0; r < 4; r++) ((float*)lds_acc)[t + 512 * r] = 0.f;

    const short* qrowA = Qf + (qbase + lr) * 64 + lg * 8;
    const short* qrowB = qrowA + 16 * 64;
    bf16x8 qA0 = *(const bf16x8*)(qrowA);
    bf16x8 qA1 = *(const bf16x8*)(qrowA + 32);
    bf16x8 qB0 = *(const bf16x8*)(qrowB);
    bf16x8 qB1 = *(const bf16x8*)(qrowB + 32);

    float mA = -1e30f, sA = 0.f, mB = -1e30f, sB = 0.f;
    f32x4 zv = {0,0,0,0};
    f32x4 accA[4], accB[4];
    #pragma unroll
    for (int i = 0; i < 4; i++) { accA[i] = zv; accB[i] = zv; }

    int perm = (lr & 3) + 8 * (lr >> 2);   // K-row permutation: st regs -> j = 8*lg + i
    int jstart = wave * 1152;
    for (int it = 0; it < 36; it++) {
        int jb = jstart + it * 32;
        const short* kp = Kf + (jb + perm) * 64 + lg * 8;
        bf16x8 k00 = *(const bf16x8*)(kp);
        bf16x8 k01 = *(const bf16x8*)(kp + 32);
        bf16x8 k10 = *(const bf16x8*)(kp + 256);       // +4 rows
        bf16x8 k11 = *(const bf16x8*)(kp + 256 + 32);
        f32x4 st00 = MFMA(k00, qA0, zv); st00 = MFMA(k01, qA1, st00);
        f32x4 st10 = MFMA(k10, qA0, zv); st10 = MFMA(k11, qA1, st10);
        f32x4 st01 = MFMA(k00, qB0, zv); st01 = MFMA(k01, qB1, st01);
        f32x4 st11 = MFMA(k10, qB0, zv); st11 = MFMA(k11, qB1, st11);

        // ---- online softmax, q-subtile A (q = qbase+lr)
        float tm = fmaxf(fmaxf(fmaxf(st00[0], st00[1]), fmaxf(st00[2], st00[3])),
                         fmaxf(fmaxf(st10[0], st10[1]), fmaxf(st10[2], st10[3])));
        tm = fmaxf(tm, __shfl_xor(tm, 16));
        tm = fmaxf(tm, __shfl_xor(tm, 32));
        float mnA = fmaxf(mA, tm);
        float scA = __expf(mA - mnA);
        float pA0 = __expf(st00[0] - mnA), pA1 = __expf(st00[1] - mnA);
        float pA2 = __expf(st00[2] - mnA), pA3 = __expf(st00[3] - mnA);
        float pA4 = __expf(st10[0] - mnA), pA5 = __expf(st10[1] - mnA);
        float pA6 = __expf(st10[2] - mnA), pA7 = __expf(st10[3] - mnA);
        float ps = pA0 + pA1 + pA2 + pA3 + pA4 + pA5 + pA6 + pA7;
        ps += __shfl_xor(ps, 16); ps += __shfl_xor(ps, 32);
        sA = sA * scA + ps; mA = mnA;
        bf16x8 pbA;
        pbA[0] = f2b(pA0); pbA[1] = f2b(pA1); pbA[2] = f2b(pA2); pbA[3] = f2b(pA3);
        pbA[4] = f2b(pA4); pbA[5] = f2b(pA5); pbA[6] = f2b(pA6); pbA[7] = f2b(pA7);

        // ---- q-subtile B (q = qbase+16+lr)
        tm = fmaxf(fmaxf(fmaxf(st01[0], st01[1]), fmaxf(st01[2], st01[3])),
                   fmaxf(fmaxf(st11[0], st11[1]), fmaxf(st11[2], st11[3])));
        tm = fmaxf(tm, __shfl_xor(tm, 16));
        tm = fmaxf(tm, __shfl_xor(tm, 32));
        float mnB = fmaxf(mB, tm);
        float scB = __expf(mB - mnB);
        float pB0 = __expf(st01[0] - mnB), pB1 = __expf(st01[1] - mnB);
        float pB2 = __expf(st01[2] - mnB), pB3 = __expf(st01[3] - mnB);
        float pB4 = __expf(st11[0] - mnB), pB5 = __expf(st11[1] - mnB);
        float pB6 = __expf(st11[2] - mnB), pB7 = __expf(st11[3] - mnB);
        ps = pB0 + pB1 + pB2 + pB3 + pB4 + pB5 + pB6 + pB7;
        ps += __shfl_xor(ps, 16); ps += __shfl_xor(ps, 32);
        sB = sB * scB + ps; mB = mnB;
        bf16x8 pbB;
        pbB[0] = f2b(pB0); pbB[1] = f2b(pB1); pbB[2] = f2b(pB2); pbB[3] = f2b(pB3);
        pbB[4] = f2b(pB4); pbB[5] = f2b(pB5); pbB[6] = f2b(pB6); pbB[7] = f2b(pB7);

        // ---- PV: O^T[dv][q] += V^T @ P^T
        const short* vp = Vt + lr * 9216 + jb + lg * 8;
        #pragma unroll
        for (int dvt = 0; dvt < 4; dvt++) {
            bf16x8 vf = *(const bf16x8*)(vp + dvt * 16 * 9216);
            accA[dvt] = MFMA(vf, pbA, accA[dvt] * scA);
            accB[dvt] = MFMA(vf, pbB, accB[dvt] * scB);
        }
    }

    // ---- combine the 8 KV chunks
    if (lane < 16) {
        lds_m[wave][lane] = mA;      lds_s[wave][lane] = sA;
        lds_m[wave][16 + lane] = mB; lds_s[wave][16 + lane] = sB;
    }
    __syncthreads();
    float mgA = lds_m[0][lr], mgB = lds_m[0][16 + lr];
    #pragma unroll
    for (int w = 1; w < 8; w++) {
        mgA = fmaxf(mgA, lds_m[w][lr]);
        mgB = fmaxf(mgB, lds_m[w][16 + lr]);
    }
    float fA = __expf(mA - mgA), fB = __expf(mB - mgB);
    #pragma unroll
    for (int dvt = 0; dvt < 4; dvt++) {
        #pragma unroll
        for (int i = 0; i < 4; i++) {
            atomicAdd(&lds_acc[dvt * 16 + 4 * lg + i][lr],      accA[dvt][i] * fA);
            atomicAdd(&lds_acc[dvt * 16 + 4 * lg + i][16 + lr], accB[dvt][i] * fB);
        }
    }
    __syncthreads();
    #pragma unroll
    for (int r = 0; r < 4; r++) {
        int idx = t + 512 * r;
        int dv = idx >> 5, q = idx & 31;
        float mg = lds_m[0][q];
        #pragma unroll
        for (int w = 1; w < 8; w++) mg = fmaxf(mg, lds_m[w][q]);
        float S = 0.f;
        #pragma unroll
        for (int w = 0; w < 8; w++) S += lds_s[w][q] * __expf(lds_m[w][q] - mg);
        int n = qbase + q, p = n >> 2, hh = n & 3;
        Of[p * 256 + hh * 64 + dv] = f2b(lds_acc[dv][q] / S);
    }
}

// ---------- output projection: out[256][2304] = Wo @ Of^T + bo (fp32 out, NCHW)
__global__ __launch_bounds__(256) void k_gemm_out(
    const short* __restrict__ Wo_bf, const short* __restrict__ Of,
    const float* __restrict__ bo, float* __restrict__ out) {
    int t = threadIdx.x, wave = t >> 6, lane = t & 63, lr = lane & 15, lg = lane >> 4;
    int obase = blockIdx.x * 64 + wave * 16;   // grid.x = 4
    int pbase = blockIdx.y * 64;               // grid.y = 36
    const short* arow  = Wo_bf + (obase + lr) * 256 + lg * 8;
    const short* brow0 = Of + (pbase +  0 + lr) * 256 + lg * 8;
    const short* brow1 = Of + (pbase + 16 + lr) * 256 + lg * 8;
    const short* brow2 = Of + (pbase + 32 + lr) * 256 + lg * 8;
    const short* brow3 = Of + (pbase + 48 + lr) * 256 + lg * 8;
    f32x4 acc0 = {0,0,0,0}, acc1 = {0,0,0,0}, acc2 = {0,0,0,0}, acc3 = {0,0,0,0};
    #pragma unroll
    for (int ks = 0; ks < 8; ks++) {
        bf16x8 a = *(const bf16x8*)(arow + ks * 32);
        acc0 = MFMA(a, *(const bf16x8*)(brow0 + ks * 32), acc0);
        acc1 = MFMA(a, *(const bf16x8*)(brow1 + ks * 32), acc1);
        acc2 = MFMA(a, *(const bf16x8*)(brow2 + ks * 32), acc2);
        acc3 = MFMA(a, *(const bf16x8*)(brow3 + ks * 32), acc3);
    }
    f32x4 accs[4] = {acc0, acc1, acc2, acc3};
    #pragma unroll
    for (int i = 0; i < 4; i++) {
        int o = obase + 4 * lg + i;
        float b = bo[o];
        #pragma unroll
        for (int ct = 0; ct < 4; ct++) {
            int p = pbase + ct * 16 + lr;
            out[o * 2304 + p] = accs[ct][i] + b;
        }
    }
}

extern "C" void kernel_launch(void* const* d_in, const int* in_sizes, int n_in,
                              void* d_out, int out_size, void* d_ws, size_t ws_size,
                              hipStream_t stream) {
    const float* x  = (const float*)d_in[0];
    const float* Wq = (const float*)d_in[1];
    const float* bq = (const float*)d_in[2];
    const float* Wk = (const float*)d_in[3];
    const float* bk = (const float*)d_in[4];
    const float* Wv = (const float*)d_in[5];
    const float* bv = (const float*)d_in[6];
    const float* Wo = (const float*)d_in[7];
    const float* bo = (const float*)d_in[8];

    char* ws = (char*)d_ws;
    short* Wall = (short*)(ws);                     // 1024*256*2 = 524288 B
    short* xt   = (short*)(ws + 524288);            // 2304*256*2 = 1179648 B
    short* Qf   = (short*)(ws + 1703936);           // 9216*64*2
    short* Kf   = (short*)(ws + 2883584);           // 9216*64*2
    short* Vt   = (short*)(ws + 4063232);           // 64*9216*2
    short* Of   = (short*)(ws + 5242880);           // 2304*256*2  (end: 6422528 B)
    float* out  = (float*)d_out;

    k_cast_w<<<1024, 256, 0, stream>>>(Wq, Wk, Wv, Wo, Wall);
    k_transpose_x<<<dim3(36, 4), 256, 0, stream>>>(x, xt);
    k_gemm_qkv<<<dim3(12, 36), 256, 0, stream>>>(Wall, xt, bq, bk, bv, Qf, Kf, Vt);
    k_attn<<<288, 512, 0, stream>>>(Qf, Kf, Vt, Of);
    k_gemm_out<<<dim3(4, 36), 256, 0, stream>>>(Wall + 768 * 256, Of, bo, out);
}